// Round 1
// baseline (1305.898 us; speedup 1.0000x reference)
//
#include <hip/hip_runtime.h>
#include <hip/hip_bf16.h>

typedef __attribute__((ext_vector_type(8))) short short8;
typedef __attribute__((ext_vector_type(4))) float f32x4;

#define TP 46  // active time steps: 30 strided + 16 dense

__device__ __forceinline__ unsigned short f2bf(float f) {
  unsigned int u = __float_as_uint(f);
  u = (u + 0x7fff + ((u >> 16) & 1)) >> 16;
  return (unsigned short)u;
}

__device__ __forceinline__ int act_t(int j) { return j < 30 ? (j << 3) : (210 + j); }

// ---------------- weight convert + transpose to bf16 ----------------
// pool layout (elem offsets): WQt 0, WKt 65536, WVt 131072, WOt 196608,
// WQs 262144, WKs 327680, WVs 393216, WOs 458752, W1T 524288 [1024][256],
// W2T 786432 [256][1024]. All stored as WT[c][k] for B-fragment reads.
__global__ __launch_bounds__(256) void convw_kernel(
    const float* __restrict__ wq_t, const float* __restrict__ wk_t,
    const float* __restrict__ wv_t, const float* __restrict__ wo_t,
    const float* __restrict__ wq_s, const float* __restrict__ wk_s,
    const float* __restrict__ wv_s, const float* __restrict__ wo_s,
    const float* __restrict__ w1, const float* __restrict__ w2,
    unsigned short* __restrict__ pool) {
  int idx = blockIdx.x * 256 + threadIdx.x;
  float v;
  if (idx < 524288) {
    int seg = idx >> 16, local = idx & 65535;
    const float* s = (seg == 0) ? wq_t : (seg == 1) ? wk_t : (seg == 2) ? wv_t :
                     (seg == 3) ? wo_t : (seg == 4) ? wq_s : (seg == 5) ? wk_s :
                     (seg == 6) ? wv_s : wo_s;
    int c = local >> 8, k = local & 255;
    v = s[k * 256 + c];
  } else if (idx < 786432) {
    int local = idx - 524288;           // W1T [1024][256]
    int c = local >> 8, k = local & 255;
    v = w1[k * 1024 + c];
  } else {
    int local = idx - 786432;           // W2T [256][1024]
    int c = local >> 10, k = local & 1023;
    v = w2[k * 256 + c];
  }
  pool[idx] = f2bf(v);
}

// ---------------- rmsnorm (fp32 -> bf16), one wave per row of 256 ----------------
__global__ __launch_bounds__(256) void rms_kernel(const float* __restrict__ src,
    const float* __restrict__ w, unsigned short* __restrict__ dst, int rows) {
  int wv = threadIdx.x >> 6, lane = threadIdx.x & 63;
  int row = (blockIdx.x << 2) + wv;
  if (row >= rows) return;
  const float4 x = *(const float4*)(src + (size_t)row * 256 + lane * 4);
  float ss = x.x * x.x + x.y * x.y + x.z * x.z + x.w * x.w;
  #pragma unroll
  for (int off = 1; off < 64; off <<= 1) ss += __shfl_xor(ss, off, 64);
  float sc = rsqrtf(ss * 0.00390625f + 1e-6f);
  const float4 wt = *(const float4*)(w + lane * 4);
  ushort4 o;
  o.x = f2bf(x.x * sc * wt.x); o.y = f2bf(x.y * sc * wt.y);
  o.z = f2bf(x.z * sc * wt.z); o.w = f2bf(x.w * sc * wt.w);
  *(ushort4*)(dst + (size_t)row * 256 + lane * 4) = o;
}

// rmsnorm over gathered rows: stage-2 row (b*TP+j)*256+n  <-  h[b, n, act(j), :]
__global__ __launch_bounds__(256) void rms_gather_kernel(const float* __restrict__ hsrc,
    const float* __restrict__ w, unsigned short* __restrict__ dst, int rows, int row_base) {
  int wv = threadIdx.x >> 6, lane = threadIdx.x & 63;
  int row = (blockIdx.x << 2) + wv;
  if (row >= rows) return;
  int gr = row_base + row;
  int b = gr / 11776; int rem = gr - b * 11776;
  int j = rem >> 8, n = rem & 255;
  const float* src = hsrc + (((size_t)((b << 8) + n) << 8) + act_t(j)) * 256;
  const float4 x = *(const float4*)(src + lane * 4);
  float ss = x.x * x.x + x.y * x.y + x.z * x.z + x.w * x.w;
  #pragma unroll
  for (int off = 1; off < 64; off <<= 1) ss += __shfl_xor(ss, off, 64);
  float sc = rsqrtf(ss * 0.00390625f + 1e-6f);
  const float4 wt = *(const float4*)(w + lane * 4);
  ushort4 o;
  o.x = f2bf(x.x * sc * wt.x); o.y = f2bf(x.y * sc * wt.y);
  o.z = f2bf(x.z * sc * wt.z); o.w = f2bf(x.w * sc * wt.w);
  *(ushort4*)(dst + (size_t)row * 256 + lane * 4) = o;
}

// ---------------- GEMM: X[rows x 256] (bf16) @ W (as WT[256][256] bf16) ----------------
// MODE 0: Y bf16.  MODE 1: outf = resid + X@W (fp32).  MODE 2: scatter-add into h.
template<int MODE>
__global__ __launch_bounds__(256) void gemm256_kernel(
    const unsigned short* __restrict__ X, const unsigned short* __restrict__ WT,
    unsigned short* __restrict__ Yb, const float* __restrict__ resid,
    float* __restrict__ outf, int row_base) {
  int wv = threadIdx.x >> 6, lane = threadIdx.x & 63;
  int lr = lane & 15, lg = lane >> 4;
  int row0 = blockIdx.x * 128 + wv * 32;
  f32x4 zero = {0.f, 0.f, 0.f, 0.f};
  f32x4 acc[2][16];
  #pragma unroll
  for (int i = 0; i < 2; ++i)
    #pragma unroll
    for (int ct = 0; ct < 16; ++ct) acc[i][ct] = zero;
  #pragma unroll
  for (int ks = 0; ks < 8; ++ks) {
    short8 a0 = *(const short8*)(X + (size_t)(row0 + lr) * 256 + ks * 32 + lg * 8);
    short8 a1 = *(const short8*)(X + (size_t)(row0 + 16 + lr) * 256 + ks * 32 + lg * 8);
    #pragma unroll
    for (int ct = 0; ct < 16; ++ct) {
      short8 bw = *(const short8*)(WT + (size_t)(ct * 16 + lr) * 256 + ks * 32 + lg * 8);
      acc[0][ct] = __builtin_amdgcn_mfma_f32_16x16x32_bf16(a0, bw, acc[0][ct], 0, 0, 0);
      acc[1][ct] = __builtin_amdgcn_mfma_f32_16x16x32_bf16(a1, bw, acc[1][ct], 0, 0, 0);
    }
  }
  #pragma unroll
  for (int i = 0; i < 2; ++i) {
    #pragma unroll
    for (int ct = 0; ct < 16; ++ct) {
      #pragma unroll
      for (int r = 0; r < 4; ++r) {
        int row = row0 + i * 16 + lg * 4 + r;
        int col = ct * 16 + lr;
        float v = acc[i][ct][r];
        if (MODE == 0) {
          Yb[(size_t)row * 256 + col] = f2bf(v);
        } else if (MODE == 1) {
          size_t o = (size_t)row * 256 + col;
          outf[o] = resid[o] + v;
        } else {
          int gr = row_base + row;
          int b = gr / 11776; int rem = gr - b * 11776;
          int j = rem >> 8, n = rem & 255;
          size_t o = (((size_t)((b << 8) + n) << 8) + act_t(j)) * 256 + col;
          outf[o] += v;
        }
      }
    }
  }
}

// ---------------- attention: one block per (head, seq); seq len 256, hdim 32 ----------------
__global__ __launch_bounds__(256) void attn_kernel(
    const unsigned short* __restrict__ Q, const unsigned short* __restrict__ K,
    const unsigned short* __restrict__ V, unsigned short* __restrict__ O,
    const int* __restrict__ mask, int seq_base) {
  __shared__ unsigned short Ksh[256][40];    // padded: 2-way max bank conflict
  __shared__ unsigned short Vtsh[32][264];   // V transposed [d][key]
  __shared__ unsigned short Psh[4][16][264]; // per-wave P transpose buffer
  int head = blockIdx.x, seq = blockIdx.y;
  int hc = head * 32;
  size_t sb = (size_t)seq * 65536;
  int tid = threadIdx.x;
  {
    int r = tid;  // one row per thread
    #pragma unroll
    for (int c = 0; c < 4; ++c) {
      *(short8*)&Ksh[r][c * 8] = *(const short8*)(K + sb + (size_t)r * 256 + hc + c * 8);
      short8 vv = *(const short8*)(V + sb + (size_t)r * 256 + hc + c * 8);
      #pragma unroll
      for (int e = 0; e < 8; ++e) Vtsh[c * 8 + e][r] = (unsigned short)vv[e];
    }
  }
  __syncthreads();
  int wv = tid >> 6, lane = tid & 63, lr = lane & 15, lg = lane >> 4;
  const float scale = 0.17677669529663687f;  // 1/sqrt(32)
  int mb = 0;
  if (mask) mb = (seq_base + seq) / TP;
  f32x4 zero = {0.f, 0.f, 0.f, 0.f};
  for (int rt = 0; rt < 4; ++rt) {
    int row0 = wv * 64 + rt * 16;
    short8 aq = *(const short8*)(Q + sb + (size_t)(row0 + lr) * 256 + hc + lg * 8);
    f32x4 s[16];
    #pragma unroll
    for (int ct = 0; ct < 16; ++ct) {
      short8 kb = *(const short8*)&Ksh[ct * 16 + lr][lg * 8];
      s[ct] = __builtin_amdgcn_mfma_f32_16x16x32_bf16(aq, kb, zero, 0, 0, 0);
    }
    #pragma unroll
    for (int ct = 0; ct < 16; ++ct) {
      bool keep = true;
      if (mask) keep = (mask[mb * 256 + ct * 16 + lr] != 0);
      #pragma unroll
      for (int r = 0; r < 4; ++r) {
        float v = s[ct][r] * scale;
        s[ct][r] = keep ? v : -1e9f;
      }
    }
    float mx[4] = {-3e38f, -3e38f, -3e38f, -3e38f};
    #pragma unroll
    for (int ct = 0; ct < 16; ++ct)
      #pragma unroll
      for (int r = 0; r < 4; ++r) mx[r] = fmaxf(mx[r], s[ct][r]);
    #pragma unroll
    for (int off = 1; off < 16; off <<= 1)
      #pragma unroll
      for (int r = 0; r < 4; ++r) mx[r] = fmaxf(mx[r], __shfl_xor(mx[r], off, 64));
    float sum[4] = {0.f, 0.f, 0.f, 0.f};
    #pragma unroll
    for (int ct = 0; ct < 16; ++ct)
      #pragma unroll
      for (int r = 0; r < 4; ++r) {
        float p = __expf(s[ct][r] - mx[r]);
        s[ct][r] = p; sum[r] += p;
      }
    #pragma unroll
    for (int off = 1; off < 16; off <<= 1)
      #pragma unroll
      for (int r = 0; r < 4; ++r) sum[r] += __shfl_xor(sum[r], off, 64);
    float inv[4];
    #pragma unroll
    for (int r = 0; r < 4; ++r) inv[r] = 1.0f / sum[r];
    #pragma unroll
    for (int ct = 0; ct < 16; ++ct)
      #pragma unroll
      for (int r = 0; r < 4; ++r)
        Psh[wv][lg * 4 + r][ct * 16 + lr] = f2bf(s[ct][r] * inv[r]);
    f32x4 o[2] = {zero, zero};
    #pragma unroll
    for (int ks = 0; ks < 8; ++ks) {
      short8 pa = *(const short8*)&Psh[wv][lr][ks * 32 + lg * 8];
      #pragma unroll
      for (int c2 = 0; c2 < 2; ++c2) {
        short8 vbf = *(const short8*)&Vtsh[c2 * 16 + lr][ks * 32 + lg * 8];
        o[c2] = __builtin_amdgcn_mfma_f32_16x16x32_bf16(pa, vbf, o[c2], 0, 0, 0);
      }
    }
    #pragma unroll
    for (int c2 = 0; c2 < 2; ++c2)
      #pragma unroll
      for (int r = 0; r < 4; ++r)
        O[sb + (size_t)(row0 + lg * 4 + r) * 256 + hc + c2 * 16 + lr] = f2bf(o[c2][r]);
  }
}

// ---------------- fused FFN: out += gelu(X@W1+b1)@W2 + b2 ----------------
__global__ __launch_bounds__(256) void ffn_kernel(
    const unsigned short* __restrict__ X, const unsigned short* __restrict__ W1T,
    const unsigned short* __restrict__ W2T, const float* __restrict__ b1,
    const float* __restrict__ b2, float* __restrict__ out) {
  __shared__ unsigned short W1sh[64][264];
  __shared__ unsigned short W2sh[256][72];
  __shared__ unsigned short Psh[4][16][72];
  int tid = threadIdx.x;
  int wv = tid >> 6, lane = tid & 63, lr = lane & 15, lg = lane >> 4;
  int wrow = blockIdx.x * 64 + wv * 16;
  f32x4 zero = {0.f, 0.f, 0.f, 0.f};
  f32x4 oacc[16];
  #pragma unroll
  for (int ct = 0; ct < 16; ++ct) oacc[ct] = zero;
  short8 afrag[8];  // this wave's 16 rows of X: hoisted, reused across all FF chunks
  #pragma unroll
  for (int ks = 0; ks < 8; ++ks)
    afrag[ks] = *(const short8*)(X + (size_t)(wrow + lr) * 256 + ks * 32 + lg * 8);
  for (int fc = 0; fc < 16; ++fc) {
    __syncthreads();
    #pragma unroll
    for (int c = 0; c < 8; ++c) {
      int chunk = tid * 8 + c;
      int r = chunk >> 5, cc = chunk & 31;
      *(short8*)&W1sh[r][cc * 8] = *(const short8*)(W1T + (size_t)(fc * 64 + r) * 256 + cc * 8);
    }
    #pragma unroll
    for (int c = 0; c < 8; ++c) {
      int chunk = tid * 8 + c;
      int r = chunk >> 3, cc = chunk & 7;
      *(short8*)&W2sh[r][cc * 8] = *(const short8*)(W2T + (size_t)r * 1024 + fc * 64 + cc * 8);
    }
    __syncthreads();
    f32x4 hacc[4];
    #pragma unroll
    for (int ct = 0; ct < 4; ++ct) hacc[ct] = zero;
    #pragma unroll
    for (int ks = 0; ks < 8; ++ks) {
      #pragma unroll
      for (int ct = 0; ct < 4; ++ct) {
        short8 bw = *(const short8*)&W1sh[ct * 16 + lr][ks * 32 + lg * 8];
        hacc[ct] = __builtin_amdgcn_mfma_f32_16x16x32_bf16(afrag[ks], bw, hacc[ct], 0, 0, 0);
      }
    }
    #pragma unroll
    for (int ct = 0; ct < 4; ++ct)
      #pragma unroll
      for (int r = 0; r < 4; ++r) {
        float hv = hacc[ct][r] + b1[fc * 64 + ct * 16 + lr];
        // tanh-approx gelu == hv * sigmoid(2*0.7978845608*(hv + 0.044715 hv^3))
        float g = hv / (1.0f + __expf(-1.5957691216057308f * (hv + 0.044715f * hv * hv * hv)));
        Psh[wv][lg * 4 + r][ct * 16 + lr] = f2bf(g);
      }
    #pragma unroll
    for (int ks = 0; ks < 2; ++ks) {
      short8 pa = *(const short8*)&Psh[wv][lr][ks * 32 + lg * 8];
      #pragma unroll
      for (int ct = 0; ct < 16; ++ct) {
        short8 bw = *(const short8*)&W2sh[ct * 16 + lr][ks * 32 + lg * 8];
        oacc[ct] = __builtin_amdgcn_mfma_f32_16x16x32_bf16(pa, bw, oacc[ct], 0, 0, 0);
      }
    }
  }
  #pragma unroll
  for (int ct = 0; ct < 16; ++ct)
    #pragma unroll
    for (int r = 0; r < 4; ++r) {
      int row = wrow + lg * 4 + r, col = ct * 16 + lr;
      size_t o = (size_t)row * 256 + col;
      out[o] += oacc[ct][r] + b2[col];
    }
}

extern "C" void kernel_launch(void* const* d_in, const int* in_sizes, int n_in,
                              void* d_out, int out_size, void* d_ws, size_t ws_size,
                              hipStream_t stream) {
  (void)in_sizes; (void)n_in; (void)out_size;
  const float* h   = (const float*)d_in[0];
  const int* smask = (const int*)d_in[1];
  const float* ntw = (const float*)d_in[2];
  const float* nsw = (const float*)d_in[3];
  const float* nfw = (const float*)d_in[4];
  const float* wq_t = (const float*)d_in[5];
  const float* wk_t = (const float*)d_in[6];
  const float* wv_t = (const float*)d_in[7];
  const float* wo_t = (const float*)d_in[8];
  const float* wq_s = (const float*)d_in[9];
  const float* wk_s = (const float*)d_in[10];
  const float* wv_s = (const float*)d_in[11];
  const float* wo_s = (const float*)d_in[12];
  const float* w1  = (const float*)d_in[13];
  const float* b1  = (const float*)d_in[14];
  const float* w2  = (const float*)d_in[15];
  const float* b2  = (const float*)d_in[16];
  float* out = (float*)d_out;
  unsigned short* pool = (unsigned short*)d_ws;

  unsigned short* WQt = pool;
  unsigned short* WKt = pool + 65536;
  unsigned short* WVt = pool + 131072;
  unsigned short* WOt = pool + 196608;
  unsigned short* WQs = pool + 262144;
  unsigned short* WKs = pool + 327680;
  unsigned short* WVs = pool + 393216;
  unsigned short* WOs = pool + 458752;
  unsigned short* W1T = pool + 524288;
  unsigned short* W2T = pool + 786432;

  size_t wbytes = 1048576ull * 2;
  size_t avail = (ws_size > wbytes) ? (ws_size - wbytes) : 0;
  long long scl = (long long)(avail / 524288ull);  // 4 buffers x 128KB per sequence
  int SC = scl < 1 ? 1 : (scl > 512 ? 512 : (int)scl);
  unsigned short* xnorm = pool + 1048576;  // also aliased as attention output
  unsigned short* qb = xnorm + (size_t)SC * 65536;
  unsigned short* kb = qb + (size_t)SC * 65536;
  unsigned short* vb = kb + (size_t)SC * 65536;

  convw_kernel<<<4096, 256, 0, stream>>>(wq_t, wk_t, wv_t, wo_t, wq_s, wk_s, wv_s,
                                         wo_s, w1, w2, pool);

  // ---- stage 1: time attention over (b,n) sequences (512 of them) ----
  for (int s0 = 0; s0 < 512; s0 += SC) {
    int ns = (512 - s0 < SC) ? (512 - s0) : SC;
    int rows = ns * 256;
    rms_kernel<<<rows / 4, 256, 0, stream>>>(h + (size_t)s0 * 65536, ntw, xnorm, rows);
    gemm256_kernel<0><<<rows / 128, 256, 0, stream>>>(xnorm, WQt, qb, nullptr, nullptr, 0);
    gemm256_kernel<0><<<rows / 128, 256, 0, stream>>>(xnorm, WKt, kb, nullptr, nullptr, 0);
    gemm256_kernel<0><<<rows / 128, 256, 0, stream>>>(xnorm, WVt, vb, nullptr, nullptr, 0);
    attn_kernel<<<dim3(8, ns), 256, 0, stream>>>(qb, kb, vb, xnorm, nullptr, 0);
    gemm256_kernel<1><<<rows / 128, 256, 0, stream>>>(xnorm, WOt, nullptr,
        h + (size_t)s0 * 65536, out + (size_t)s0 * 65536, 0);
  }

  // ---- stage 2: stock attention over gathered active-t slices (92 sequences) ----
  int SC2 = SC < 92 ? SC : 92;
  for (int s0 = 0; s0 < 92; s0 += SC2) {
    int ns = (92 - s0 < SC2) ? (92 - s0) : SC2;
    int rows = ns * 256;
    rms_gather_kernel<<<rows / 4, 256, 0, stream>>>(out, nsw, xnorm, rows, s0 * 256);
    gemm256_kernel<0><<<rows / 128, 256, 0, stream>>>(xnorm, WQs, qb, nullptr, nullptr, 0);
    gemm256_kernel<0><<<rows / 128, 256, 0, stream>>>(xnorm, WKs, kb, nullptr, nullptr, 0);
    gemm256_kernel<0><<<rows / 128, 256, 0, stream>>>(xnorm, WVs, vb, nullptr, nullptr, 0);
    attn_kernel<<<dim3(8, ns), 256, 0, stream>>>(qb, kb, vb, xnorm, smask, s0);
    gemm256_kernel<2><<<rows / 128, 256, 0, stream>>>(xnorm, WOs, nullptr, nullptr, out, s0 * 256);
  }

  // ---- stage 3: FFN ----
  int TCH = SC * 256;
  for (int t0 = 0; t0 < 131072; t0 += TCH) {
    int tc = (131072 - t0 < TCH) ? (131072 - t0) : TCH;
    rms_kernel<<<tc / 4, 256, 0, stream>>>(out + (size_t)t0 * 256, nfw, xnorm, tc);
    ffn_kernel<<<tc / 64, 256, 0, stream>>>(xnorm, W1T, W2T, b1, b2, out + (size_t)t0 * 256);
  }
}

// Round 2
// 1016.301 us; speedup vs baseline: 1.2850x; 1.2850x over previous
//
#include <hip/hip_runtime.h>
#include <hip/hip_bf16.h>

typedef __attribute__((ext_vector_type(8))) short short8;
typedef __attribute__((ext_vector_type(4))) float f32x4;

#define TP 46  // active time steps: 30 strided + 16 dense

__device__ __forceinline__ unsigned short f2bf(float f) {
  unsigned int u = __float_as_uint(f);
  u = (u + 0x7fff + ((u >> 16) & 1)) >> 16;
  return (unsigned short)u;
}

__device__ __forceinline__ int act_t(int j) { return j < 30 ? (j << 3) : (210 + j); }

// async 16B/lane global->LDS: lds base must be wave-uniform; HW writes lane i at base+i*16
__device__ __forceinline__ void load_lds16(const unsigned short* g, unsigned short* lds_base) {
#if __has_builtin(__builtin_amdgcn_global_load_lds)
  __builtin_amdgcn_global_load_lds(
      (const __attribute__((address_space(1))) unsigned int*)(unsigned long long)g,
      (__attribute__((address_space(3))) unsigned int*)(unsigned int)(unsigned long long)lds_base,
      16, 0, 0);
#else
  int lane = threadIdx.x & 63;
  *(short8*)(lds_base + lane * 8) = *(const short8*)g;
#endif
}

// ---------------- weight convert + transpose to bf16 ----------------
// pool layout (elem offsets): WQt 0, WKt 65536, WVt 131072, WOt 196608,
// WQs 262144, WKs 327680, WVs 393216, WOs 458752 (all WT[c][k]),
// W1F 524288, W2F 786432 (fragment-ordered for the fused FFN kernel).
// W1F: off = ((fc*2+ct)*8+ks)*512 + lane*8 + e  -> w1[(ks*32+lg*8+e)*1024 + fc*32+ct*16+lr]
// W2F: off = (fc*16+ct2)*512 + lane*8 + e2      -> w2[(fc*32+lg*8+e2)*256 + ct2*16+lr]
__global__ __launch_bounds__(256) void convw_kernel(
    const float* __restrict__ wq_t, const float* __restrict__ wk_t,
    const float* __restrict__ wv_t, const float* __restrict__ wo_t,
    const float* __restrict__ wq_s, const float* __restrict__ wk_s,
    const float* __restrict__ wv_s, const float* __restrict__ wo_s,
    const float* __restrict__ w1, const float* __restrict__ w2,
    unsigned short* __restrict__ pool) {
  int idx = blockIdx.x * 256 + threadIdx.x;
  float v;
  if (idx < 524288) {
    int seg = idx >> 16, local = idx & 65535;
    const float* s = (seg == 0) ? wq_t : (seg == 1) ? wk_t : (seg == 2) ? wv_t :
                     (seg == 3) ? wo_t : (seg == 4) ? wq_s : (seg == 5) ? wk_s :
                     (seg == 6) ? wv_s : wo_s;
    int c = local >> 8, k = local & 255;
    v = s[k * 256 + c];
  } else if (idx < 786432) {
    int local = idx - 524288;
    int e = local & 7, t = local >> 3;
    int lane = t & 63, ks = (t >> 6) & 7, ct = (t >> 9) & 1, fc = t >> 10;
    int lr = lane & 15, lg = lane >> 4;
    v = w1[(size_t)(ks * 32 + lg * 8 + e) * 1024 + fc * 32 + ct * 16 + lr];
  } else {
    int local = idx - 786432;
    int e2 = local & 7, t = local >> 3;
    int lane = t & 63, ct2 = (t >> 6) & 15, fc = t >> 10;
    int lr = lane & 15, lg = lane >> 4;
    v = w2[(size_t)(fc * 32 + lg * 8 + e2) * 256 + ct2 * 16 + lr];
  }
  pool[idx] = f2bf(v);
}

// ---------------- rmsnorm (fp32 -> bf16), one wave per row of 256 ----------------
__global__ __launch_bounds__(256) void rms_kernel(const float* __restrict__ src,
    const float* __restrict__ w, unsigned short* __restrict__ dst, int rows) {
  int wv = threadIdx.x >> 6, lane = threadIdx.x & 63;
  int row = (blockIdx.x << 2) + wv;
  if (row >= rows) return;
  const float4 x = *(const float4*)(src + (size_t)row * 256 + lane * 4);
  float ss = x.x * x.x + x.y * x.y + x.z * x.z + x.w * x.w;
  #pragma unroll
  for (int off = 1; off < 64; off <<= 1) ss += __shfl_xor(ss, off, 64);
  float sc = rsqrtf(ss * 0.00390625f + 1e-6f);
  const float4 wt = *(const float4*)(w + lane * 4);
  ushort4 o;
  o.x = f2bf(x.x * sc * wt.x); o.y = f2bf(x.y * sc * wt.y);
  o.z = f2bf(x.z * sc * wt.z); o.w = f2bf(x.w * sc * wt.w);
  *(ushort4*)(dst + (size_t)row * 256 + lane * 4) = o;
}

// rmsnorm over gathered rows: stage-2 row (b*TP+j)*256+n  <-  h[b, n, act(j), :]
__global__ __launch_bounds__(256) void rms_gather_kernel(const float* __restrict__ hsrc,
    const float* __restrict__ w, unsigned short* __restrict__ dst, int rows, int row_base) {
  int wv = threadIdx.x >> 6, lane = threadIdx.x & 63;
  int row = (blockIdx.x << 2) + wv;
  if (row >= rows) return;
  int gr = row_base + row;
  int b = gr / 11776; int rem = gr - b * 11776;
  int j = rem >> 8, n = rem & 255;
  const float* src = hsrc + (((size_t)((b << 8) + n) << 8) + act_t(j)) * 256;
  const float4 x = *(const float4*)(src + lane * 4);
  float ss = x.x * x.x + x.y * x.y + x.z * x.z + x.w * x.w;
  #pragma unroll
  for (int off = 1; off < 64; off <<= 1) ss += __shfl_xor(ss, off, 64);
  float sc = rsqrtf(ss * 0.00390625f + 1e-6f);
  const float4 wt = *(const float4*)(w + lane * 4);
  ushort4 o;
  o.x = f2bf(x.x * sc * wt.x); o.y = f2bf(x.y * sc * wt.y);
  o.z = f2bf(x.z * sc * wt.z); o.w = f2bf(x.w * sc * wt.w);
  *(ushort4*)(dst + (size_t)row * 256 + lane * 4) = o;
}

// ---------------- GEMM: X[rows x 256] (bf16) @ W (as WT[256][256] bf16) ----------------
// MODE 0: Y bf16.  MODE 1: outf = resid + X@W (fp32).  MODE 2: scatter-add into h.
template<int MODE>
__global__ __launch_bounds__(256) void gemm256_kernel(
    const unsigned short* __restrict__ X, const unsigned short* __restrict__ WT,
    unsigned short* __restrict__ Yb, const float* __restrict__ resid,
    float* __restrict__ outf, int row_base) {
  int wv = threadIdx.x >> 6, lane = threadIdx.x & 63;
  int lr = lane & 15, lg = lane >> 4;
  int row0 = blockIdx.x * 128 + wv * 32;
  f32x4 zero = {0.f, 0.f, 0.f, 0.f};
  f32x4 acc[2][16];
  #pragma unroll
  for (int i = 0; i < 2; ++i)
    #pragma unroll
    for (int ct = 0; ct < 16; ++ct) acc[i][ct] = zero;
  #pragma unroll
  for (int ks = 0; ks < 8; ++ks) {
    short8 a0 = *(const short8*)(X + (size_t)(row0 + lr) * 256 + ks * 32 + lg * 8);
    short8 a1 = *(const short8*)(X + (size_t)(row0 + 16 + lr) * 256 + ks * 32 + lg * 8);
    #pragma unroll
    for (int ct = 0; ct < 16; ++ct) {
      short8 bw = *(const short8*)(WT + (size_t)(ct * 16 + lr) * 256 + ks * 32 + lg * 8);
      acc[0][ct] = __builtin_amdgcn_mfma_f32_16x16x32_bf16(a0, bw, acc[0][ct], 0, 0, 0);
      acc[1][ct] = __builtin_amdgcn_mfma_f32_16x16x32_bf16(a1, bw, acc[1][ct], 0, 0, 0);
    }
  }
  #pragma unroll
  for (int i = 0; i < 2; ++i) {
    #pragma unroll
    for (int ct = 0; ct < 16; ++ct) {
      #pragma unroll
      for (int r = 0; r < 4; ++r) {
        int row = row0 + i * 16 + lg * 4 + r;
        int col = ct * 16 + lr;
        float v = acc[i][ct][r];
        if (MODE == 0) {
          Yb[(size_t)row * 256 + col] = f2bf(v);
        } else if (MODE == 1) {
          size_t o = (size_t)row * 256 + col;
          outf[o] = resid[o] + v;
        } else {
          int gr = row_base + row;
          int b = gr / 11776; int rem = gr - b * 11776;
          int j = rem >> 8, n = rem & 255;
          size_t o = (((size_t)((b << 8) + n) << 8) + act_t(j)) * 256 + col;
          outf[o] += v;
        }
      }
    }
  }
}

// ---------------- attention: one block per (head, seq); seq len 256, hdim 32 ----------------
__global__ __launch_bounds__(256) void attn_kernel(
    const unsigned short* __restrict__ Q, const unsigned short* __restrict__ K,
    const unsigned short* __restrict__ V, unsigned short* __restrict__ O,
    const int* __restrict__ mask, int seq_base) {
  __shared__ unsigned short Ksh[256][40];    // padded: 2-way max bank conflict
  __shared__ unsigned short Vtsh[32][264];   // V transposed [d][key]
  __shared__ unsigned short Psh[4][16][264]; // per-wave P transpose buffer
  int head = blockIdx.x, seq = blockIdx.y;
  int hc = head * 32;
  size_t sb = (size_t)seq * 65536;
  int tid = threadIdx.x;
  {
    int r = tid;  // one row per thread
    #pragma unroll
    for (int c = 0; c < 4; ++c) {
      *(short8*)&Ksh[r][c * 8] = *(const short8*)(K + sb + (size_t)r * 256 + hc + c * 8);
      short8 vv = *(const short8*)(V + sb + (size_t)r * 256 + hc + c * 8);
      #pragma unroll
      for (int e = 0; e < 8; ++e) Vtsh[c * 8 + e][r] = (unsigned short)vv[e];
    }
  }
  __syncthreads();
  int wv = tid >> 6, lane = tid & 63, lr = lane & 15, lg = lane >> 4;
  const float scale = 0.17677669529663687f;  // 1/sqrt(32)
  int mb = 0;
  if (mask) mb = (seq_base + seq) / TP;
  f32x4 zero = {0.f, 0.f, 0.f, 0.f};
  for (int rt = 0; rt < 4; ++rt) {
    int row0 = wv * 64 + rt * 16;
    short8 aq = *(const short8*)(Q + sb + (size_t)(row0 + lr) * 256 + hc + lg * 8);
    f32x4 s[16];
    #pragma unroll
    for (int ct = 0; ct < 16; ++ct) {
      short8 kb = *(const short8*)&Ksh[ct * 16 + lr][lg * 8];
      s[ct] = __builtin_amdgcn_mfma_f32_16x16x32_bf16(aq, kb, zero, 0, 0, 0);
    }
    #pragma unroll
    for (int ct = 0; ct < 16; ++ct) {
      bool keep = true;
      if (mask) keep = (mask[mb * 256 + ct * 16 + lr] != 0);
      #pragma unroll
      for (int r = 0; r < 4; ++r) {
        float v = s[ct][r] * scale;
        s[ct][r] = keep ? v : -1e9f;
      }
    }
    float mx[4] = {-3e38f, -3e38f, -3e38f, -3e38f};
    #pragma unroll
    for (int ct = 0; ct < 16; ++ct)
      #pragma unroll
      for (int r = 0; r < 4; ++r) mx[r] = fmaxf(mx[r], s[ct][r]);
    #pragma unroll
    for (int off = 1; off < 16; off <<= 1)
      #pragma unroll
      for (int r = 0; r < 4; ++r) mx[r] = fmaxf(mx[r], __shfl_xor(mx[r], off, 64));
    float sum[4] = {0.f, 0.f, 0.f, 0.f};
    #pragma unroll
    for (int ct = 0; ct < 16; ++ct)
      #pragma unroll
      for (int r = 0; r < 4; ++r) {
        float p = __expf(s[ct][r] - mx[r]);
        s[ct][r] = p; sum[r] += p;
      }
    #pragma unroll
    for (int off = 1; off < 16; off <<= 1)
      #pragma unroll
      for (int r = 0; r < 4; ++r) sum[r] += __shfl_xor(sum[r], off, 64);
    float inv[4];
    #pragma unroll
    for (int r = 0; r < 4; ++r) inv[r] = 1.0f / sum[r];
    #pragma unroll
    for (int ct = 0; ct < 16; ++ct)
      #pragma unroll
      for (int r = 0; r < 4; ++r)
        Psh[wv][lg * 4 + r][ct * 16 + lr] = f2bf(s[ct][r] * inv[r]);
    f32x4 o[2] = {zero, zero};
    #pragma unroll
    for (int ks = 0; ks < 8; ++ks) {
      short8 pa = *(const short8*)&Psh[wv][lr][ks * 32 + lg * 8];
      #pragma unroll
      for (int c2 = 0; c2 < 2; ++c2) {
        short8 vbf = *(const short8*)&Vtsh[c2 * 16 + lr][ks * 32 + lg * 8];
        o[c2] = __builtin_amdgcn_mfma_f32_16x16x32_bf16(pa, vbf, o[c2], 0, 0, 0);
      }
    }
    #pragma unroll
    for (int c2 = 0; c2 < 2; ++c2)
      #pragma unroll
      for (int r = 0; r < 4; ++r)
        O[sb + (size_t)(row0 + lg * 4 + r) * 256 + hc + c2 * 16 + lr] = f2bf(o[c2][r]);
  }
}

// ---------------- fused FFN v2: out += gelu(X@W1+b1)@W2 + b2 ----------------
// 64 rows/block, 4 waves, FF chunks of 32. Weights staged via global_load_lds
// from fragment-ordered W1F/W2F (lane-linear LDS: zero bank conflicts, no VALU).
// LDS 37.9KB -> 4 blocks/CU at VGPR<=128 (__launch_bounds__(256,4)).
__global__ __launch_bounds__(256, 4) void ffn_kernel(
    const unsigned short* __restrict__ X, const unsigned short* __restrict__ W1F,
    const unsigned short* __restrict__ W2F, const float* __restrict__ b1,
    const float* __restrict__ b2, float* __restrict__ out) {
  __shared__ unsigned short W1s[8192];       // 16KB: [(ct*8+ks)*512 + lane*8 + e]
  __shared__ unsigned short W2s[8192];       // 16KB: [ct2*512 + lane*8 + e2]
  __shared__ unsigned short Psh[4][16][40];  // 5KB per-wave P transpose
  int tid = threadIdx.x;
  int wv = tid >> 6, lane = tid & 63, lr = lane & 15, lg = lane >> 4;
  int wrow = blockIdx.x * 64 + wv * 16;
  f32x4 zero = {0.f, 0.f, 0.f, 0.f};
  f32x4 oacc[16];
  #pragma unroll
  for (int ct = 0; ct < 16; ++ct) oacc[ct] = zero;
  short8 afrag[8];  // this wave's 16 rows of X, reused across all 32 FF chunks
  #pragma unroll
  for (int ks = 0; ks < 8; ++ks)
    afrag[ks] = *(const short8*)(X + (size_t)(wrow + lr) * 256 + ks * 32 + lg * 8);
  for (int fc = 0; fc < 32; ++fc) {
    __syncthreads();  // all waves done reading previous chunk
    // stage 32KB: 32 segments of 1KB; wave wv stages segments wv*8 .. wv*8+7
    #pragma unroll
    for (int i = 0; i < 8; ++i) {
      int s = wv * 8 + i;
      if (s < 16) {
        load_lds16(W1F + (size_t)fc * 8192 + s * 512 + lane * 8, &W1s[s * 512]);
      } else {
        load_lds16(W2F + (size_t)fc * 8192 + (s - 16) * 512 + lane * 8, &W2s[(s - 16) * 512]);
      }
    }
    __syncthreads();  // staging complete (vmcnt drain + barrier)
    f32x4 hacc[2];
    hacc[0] = zero; hacc[1] = zero;
    #pragma unroll
    for (int ks = 0; ks < 8; ++ks) {
      #pragma unroll
      for (int ct = 0; ct < 2; ++ct) {
        short8 bw = *(const short8*)&W1s[(ct * 8 + ks) * 512 + lane * 8];
        hacc[ct] = __builtin_amdgcn_mfma_f32_16x16x32_bf16(afrag[ks], bw, hacc[ct], 0, 0, 0);
      }
    }
    #pragma unroll
    for (int ct = 0; ct < 2; ++ct) {
      float bb = b1[fc * 32 + ct * 16 + lr];
      #pragma unroll
      for (int r = 0; r < 4; ++r) {
        float hv = hacc[ct][r] + bb;
        // tanh-approx gelu == hv * sigmoid(2*0.7978845608*(hv + 0.044715 hv^3))
        float g = hv / (1.0f + __expf(-1.5957691216057308f * (hv + 0.044715f * hv * hv * hv)));
        Psh[wv][lg * 4 + r][ct * 16 + lr] = f2bf(g);
      }
    }
    short8 pa = *(const short8*)&Psh[wv][lr][lg * 8];
    #pragma unroll
    for (int ct2 = 0; ct2 < 16; ++ct2) {
      short8 bw2 = *(const short8*)&W2s[ct2 * 512 + lane * 8];
      oacc[ct2] = __builtin_amdgcn_mfma_f32_16x16x32_bf16(pa, bw2, oacc[ct2], 0, 0, 0);
    }
  }
  #pragma unroll
  for (int ct = 0; ct < 16; ++ct)
    #pragma unroll
    for (int r = 0; r < 4; ++r) {
      int row = wrow + lg * 4 + r, col = ct * 16 + lr;
      size_t o = (size_t)row * 256 + col;
      out[o] += oacc[ct][r] + b2[col];
    }
}

extern "C" void kernel_launch(void* const* d_in, const int* in_sizes, int n_in,
                              void* d_out, int out_size, void* d_ws, size_t ws_size,
                              hipStream_t stream) {
  (void)in_sizes; (void)n_in; (void)out_size;
  const float* h   = (const float*)d_in[0];
  const int* smask = (const int*)d_in[1];
  const float* ntw = (const float*)d_in[2];
  const float* nsw = (const float*)d_in[3];
  const float* nfw = (const float*)d_in[4];
  const float* wq_t = (const float*)d_in[5];
  const float* wk_t = (const float*)d_in[6];
  const float* wv_t = (const float*)d_in[7];
  const float* wo_t = (const float*)d_in[8];
  const float* wq_s = (const float*)d_in[9];
  const float* wk_s = (const float*)d_in[10];
  const float* wv_s = (const float*)d_in[11];
  const float* wo_s = (const float*)d_in[12];
  const float* w1  = (const float*)d_in[13];
  const float* b1  = (const float*)d_in[14];
  const float* w2  = (const float*)d_in[15];
  const float* b2  = (const float*)d_in[16];
  float* out = (float*)d_out;
  unsigned short* pool = (unsigned short*)d_ws;

  unsigned short* WQt = pool;
  unsigned short* WKt = pool + 65536;
  unsigned short* WVt = pool + 131072;
  unsigned short* WOt = pool + 196608;
  unsigned short* WQs = pool + 262144;
  unsigned short* WKs = pool + 327680;
  unsigned short* WVs = pool + 393216;
  unsigned short* WOs = pool + 458752;
  unsigned short* W1F = pool + 524288;
  unsigned short* W2F = pool + 786432;

  size_t wbytes = 1048576ull * 2;
  size_t avail = (ws_size > wbytes) ? (ws_size - wbytes) : 0;
  long long scl = (long long)(avail / 524288ull);  // 4 buffers x 128KB per sequence
  int SC = scl < 1 ? 1 : (scl > 512 ? 512 : (int)scl);
  unsigned short* xnorm = pool + 1048576;  // also aliased as attention output
  unsigned short* qb = xnorm + (size_t)SC * 65536;
  unsigned short* kb = qb + (size_t)SC * 65536;
  unsigned short* vb = kb + (size_t)SC * 65536;

  convw_kernel<<<4096, 256, 0, stream>>>(wq_t, wk_t, wv_t, wo_t, wq_s, wk_s, wv_s,
                                         wo_s, w1, w2, pool);

  // ---- stage 1: time attention over (b,n) sequences (512 of them) ----
  for (int s0 = 0; s0 < 512; s0 += SC) {
    int ns = (512 - s0 < SC) ? (512 - s0) : SC;
    int rows = ns * 256;
    rms_kernel<<<rows / 4, 256, 0, stream>>>(h + (size_t)s0 * 65536, ntw, xnorm, rows);
    gemm256_kernel<0><<<rows / 128, 256, 0, stream>>>(xnorm, WQt, qb, nullptr, nullptr, 0);
    gemm256_kernel<0><<<rows / 128, 256, 0, stream>>>(xnorm, WKt, kb, nullptr, nullptr, 0);
    gemm256_kernel<0><<<rows / 128, 256, 0, stream>>>(xnorm, WVt, vb, nullptr, nullptr, 0);
    attn_kernel<<<dim3(8, ns), 256, 0, stream>>>(qb, kb, vb, xnorm, nullptr, 0);
    gemm256_kernel<1><<<rows / 128, 256, 0, stream>>>(xnorm, WOt, nullptr,
        h + (size_t)s0 * 65536, out + (size_t)s0 * 65536, 0);
  }

  // ---- stage 2: stock attention over gathered active-t slices (92 sequences) ----
  int SC2 = SC < 92 ? SC : 92;
  for (int s0 = 0; s0 < 92; s0 += SC2) {
    int ns = (92 - s0 < SC2) ? (92 - s0) : SC2;
    int rows = ns * 256;
    rms_gather_kernel<<<rows / 4, 256, 0, stream>>>(out, nsw, xnorm, rows, s0 * 256);
    gemm256_kernel<0><<<rows / 128, 256, 0, stream>>>(xnorm, WQs, qb, nullptr, nullptr, 0);
    gemm256_kernel<0><<<rows / 128, 256, 0, stream>>>(xnorm, WKs, kb, nullptr, nullptr, 0);
    gemm256_kernel<0><<<rows / 128, 256, 0, stream>>>(xnorm, WVs, vb, nullptr, nullptr, 0);
    attn_kernel<<<dim3(8, ns), 256, 0, stream>>>(qb, kb, vb, xnorm, smask, s0);
    gemm256_kernel<2><<<rows / 128, 256, 0, stream>>>(xnorm, WOs, nullptr, nullptr, out, s0 * 256);
  }

  // ---- stage 3: FFN ----
  int TCH = SC * 256;
  for (int t0 = 0; t0 < 131072; t0 += TCH) {
    int tc = (131072 - t0 < TCH) ? (131072 - t0) : TCH;
    rms_kernel<<<tc / 4, 256, 0, stream>>>(out + (size_t)t0 * 256, nfw, xnorm, tc);
    ffn_kernel<<<tc / 64, 256, 0, stream>>>(xnorm, W1F, W2F, b1, b2, out + (size_t)t0 * 256);
  }
}

// Round 3
// 967.981 us; speedup vs baseline: 1.3491x; 1.0499x over previous
//
#include <hip/hip_runtime.h>
#include <hip/hip_bf16.h>

typedef __attribute__((ext_vector_type(8))) short short8;
typedef __attribute__((ext_vector_type(4))) float f32x4;

#define TP 46  // active time steps: 30 strided + 16 dense

__device__ __forceinline__ unsigned short f2bf(float f) {
  unsigned int u = __float_as_uint(f);
  u = (u + 0x7fff + ((u >> 16) & 1)) >> 16;
  return (unsigned short)u;
}
// round-half-up: 2 VALU ops; bias < 1ulp, fine at bf16 threshold
__device__ __forceinline__ unsigned short f2bf_fast(float f) {
  return (unsigned short)((__float_as_uint(f) + 0x8000u) >> 16);
}

__device__ __forceinline__ int act_t(int j) { return j < 30 ? (j << 3) : (210 + j); }

// async 16B/lane global->LDS: lds base must be wave-uniform; HW writes lane i at base+i*16
__device__ __forceinline__ void load_lds16(const unsigned short* g, unsigned short* lds_base) {
#if __has_builtin(__builtin_amdgcn_global_load_lds)
  __builtin_amdgcn_global_load_lds(
      (const __attribute__((address_space(1))) unsigned int*)(unsigned long long)g,
      (__attribute__((address_space(3))) unsigned int*)(unsigned int)(unsigned long long)lds_base,
      16, 0, 0);
#else
  int lane = threadIdx.x & 63;
  *(short8*)(lds_base + lane * 8) = *(const short8*)g;
#endif
}

// ---------------- weight convert + transpose to bf16 ----------------
// pool layout (elem offsets): WQt 0, WKt 65536, WVt 131072, WOt 196608,
// WQs 262144, WKs 327680, WVs 393216, WOs 458752 (all WT[c][k]),
// W1F 524288, W2F 786432 (fragment-ordered for the fused FFN kernel).
// W1F: off = ((fc*2+ct)*8+ks)*512 + lane*8 + e  -> w1[(ks*32+lg*8+e)*1024 + fc*32+ct*16+lr]
// W2F: off = (fc*16+ct2)*512 + lane*8 + e2      -> w2[(fc*32+lg*8+e2)*256 + ct2*16+lr]
__global__ __launch_bounds__(256) void convw_kernel(
    const float* __restrict__ wq_t, const float* __restrict__ wk_t,
    const float* __restrict__ wv_t, const float* __restrict__ wo_t,
    const float* __restrict__ wq_s, const float* __restrict__ wk_s,
    const float* __restrict__ wv_s, const float* __restrict__ wo_s,
    const float* __restrict__ w1, const float* __restrict__ w2,
    unsigned short* __restrict__ pool) {
  int idx = blockIdx.x * 256 + threadIdx.x;
  float v;
  if (idx < 524288) {
    int seg = idx >> 16, local = idx & 65535;
    const float* s = (seg == 0) ? wq_t : (seg == 1) ? wk_t : (seg == 2) ? wv_t :
                     (seg == 3) ? wo_t : (seg == 4) ? wq_s : (seg == 5) ? wk_s :
                     (seg == 6) ? wv_s : wo_s;
    int c = local >> 8, k = local & 255;
    v = s[k * 256 + c];
  } else if (idx < 786432) {
    int local = idx - 524288;
    int e = local & 7, t = local >> 3;
    int lane = t & 63, ks = (t >> 6) & 7, ct = (t >> 9) & 1, fc = t >> 10;
    int lr = lane & 15, lg = lane >> 4;
    v = w1[(size_t)(ks * 32 + lg * 8 + e) * 1024 + fc * 32 + ct * 16 + lr];
  } else {
    int local = idx - 786432;
    int e2 = local & 7, t = local >> 3;
    int lane = t & 63, ct2 = (t >> 6) & 15, fc = t >> 10;
    int lr = lane & 15, lg = lane >> 4;
    v = w2[(size_t)(fc * 32 + lg * 8 + e2) * 256 + ct2 * 16 + lr];
  }
  pool[idx] = f2bf(v);
}

// ---------------- rmsnorm (fp32 -> bf16), one wave per row of 256 (stage-3 only) ----------------
__global__ __launch_bounds__(256) void rms_kernel(const float* __restrict__ src,
    const float* __restrict__ w, unsigned short* __restrict__ dst, int rows) {
  int wv = threadIdx.x >> 6, lane = threadIdx.x & 63;
  int row = (blockIdx.x << 2) + wv;
  if (row >= rows) return;
  const float4 x = *(const float4*)(src + (size_t)row * 256 + lane * 4);
  float ss = x.x * x.x + x.y * x.y + x.z * x.z + x.w * x.w;
  #pragma unroll
  for (int off = 1; off < 64; off <<= 1) ss += __shfl_xor(ss, off, 64);
  float sc = rsqrtf(ss * 0.00390625f + 1e-6f);
  const float4 wt = *(const float4*)(w + lane * 4);
  ushort4 o;
  o.x = f2bf(x.x * sc * wt.x); o.y = f2bf(x.y * sc * wt.y);
  o.z = f2bf(x.z * sc * wt.z); o.w = f2bf(x.w * sc * wt.w);
  *(ushort4*)(dst + (size_t)row * 256 + lane * 4) = o;
}

// ---------------- fused rmsnorm + QKV projection ----------------
// Block: 128 rows, 4 waves x 32 rows (2 rowtiles). rms in-register (lane holds
// its A-fragment cols; shfl_xor(16),(32) completes the row sum). Then ct-outer
// over 3x16 weight coltiles, B-frags streamed from L2, fresh 8-reg accumulators.
template<int GATHER>
__global__ __launch_bounds__(256) void qkv_kernel(
    const float* __restrict__ src, const float* __restrict__ nw,
    const unsigned short* __restrict__ W,  // 3 consecutive frag-major 256x256 mats
    unsigned short* __restrict__ qb, unsigned short* __restrict__ kb,
    unsigned short* __restrict__ vb, int row_base) {
  int tid = threadIdx.x, wv = tid >> 6, lane = tid & 63, lr = lane & 15, lg = lane >> 4;
  int row0 = blockIdx.x * 128 + wv * 32;
  short8 afrag[2][8];
  #pragma unroll
  for (int rt = 0; rt < 2; ++rt) {
    int lrow = row0 + rt * 16 + lr;
    const float* rp;
    if (GATHER) {
      int gr = row_base + lrow;
      int b = gr / 11776; int rem = gr - b * 11776;
      int j = rem >> 8, n = rem & 255;
      rp = src + (((size_t)((b << 8) + n) << 8) + act_t(j)) * 256;
    } else {
      rp = src + (size_t)lrow * 256;
    }
    float4 x[16];
    #pragma unroll
    for (int ks = 0; ks < 8; ++ks) {
      x[ks * 2]     = *(const float4*)(rp + ks * 32 + lg * 8);
      x[ks * 2 + 1] = *(const float4*)(rp + ks * 32 + lg * 8 + 4);
    }
    float ss = 0.f;
    #pragma unroll
    for (int i = 0; i < 16; ++i)
      ss += x[i].x * x[i].x + x[i].y * x[i].y + x[i].z * x[i].z + x[i].w * x[i].w;
    ss += __shfl_xor(ss, 16, 64);
    ss += __shfl_xor(ss, 32, 64);
    float sc = rsqrtf(ss * 0.00390625f + 1e-6f);
    #pragma unroll
    for (int ks = 0; ks < 8; ++ks) {
      float4 w0 = *(const float4*)(nw + ks * 32 + lg * 8);
      float4 w1_ = *(const float4*)(nw + ks * 32 + lg * 8 + 4);
      short8 af;
      af[0] = (short)f2bf(x[ks * 2].x * sc * w0.x);
      af[1] = (short)f2bf(x[ks * 2].y * sc * w0.y);
      af[2] = (short)f2bf(x[ks * 2].z * sc * w0.z);
      af[3] = (short)f2bf(x[ks * 2].w * sc * w0.w);
      af[4] = (short)f2bf(x[ks * 2 + 1].x * sc * w1_.x);
      af[5] = (short)f2bf(x[ks * 2 + 1].y * sc * w1_.y);
      af[6] = (short)f2bf(x[ks * 2 + 1].z * sc * w1_.z);
      af[7] = (short)f2bf(x[ks * 2 + 1].w * sc * w1_.w);
      afrag[rt][ks] = af;
    }
  }
  f32x4 zero = {0.f, 0.f, 0.f, 0.f};
  #pragma unroll
  for (int m = 0; m < 3; ++m) {
    unsigned short* dst = (m == 0) ? qb : (m == 1) ? kb : vb;
    const unsigned short* wb = W + m * 65536;
    #pragma unroll 4
    for (int ct = 0; ct < 16; ++ct) {
      short8 bw[8];
      #pragma unroll
      for (int ks = 0; ks < 8; ++ks)
        bw[ks] = *(const short8*)(wb + (size_t)(ct * 16 + lr) * 256 + ks * 32 + lg * 8);
      f32x4 a0 = zero, a1 = zero;
      #pragma unroll
      for (int ks = 0; ks < 8; ++ks) {
        a0 = __builtin_amdgcn_mfma_f32_16x16x32_bf16(afrag[0][ks], bw[ks], a0, 0, 0, 0);
        a1 = __builtin_amdgcn_mfma_f32_16x16x32_bf16(afrag[1][ks], bw[ks], a1, 0, 0, 0);
      }
      #pragma unroll
      for (int r = 0; r < 4; ++r) {
        dst[(size_t)(row0 + lg * 4 + r) * 256 + ct * 16 + lr] = f2bf(a0[r]);
        dst[(size_t)(row0 + 16 + lg * 4 + r) * 256 + ct * 16 + lr] = f2bf(a1[r]);
      }
    }
  }
}

// ---------------- GEMM: X[rows x 256] (bf16) @ W (as WT[256][256] bf16) ----------------
// MODE 1: outf = resid + X@W (fp32).  MODE 2: scatter-add into h.
template<int MODE>
__global__ __launch_bounds__(256) void gemm256_kernel(
    const unsigned short* __restrict__ X, const unsigned short* __restrict__ WT,
    const float* __restrict__ resid, float* __restrict__ outf, int row_base) {
  int wv = threadIdx.x >> 6, lane = threadIdx.x & 63;
  int lr = lane & 15, lg = lane >> 4;
  int row0 = blockIdx.x * 128 + wv * 32;
  f32x4 zero = {0.f, 0.f, 0.f, 0.f};
  f32x4 acc[2][16];
  #pragma unroll
  for (int i = 0; i < 2; ++i)
    #pragma unroll
    for (int ct = 0; ct < 16; ++ct) acc[i][ct] = zero;
  #pragma unroll
  for (int ks = 0; ks < 8; ++ks) {
    short8 a0 = *(const short8*)(X + (size_t)(row0 + lr) * 256 + ks * 32 + lg * 8);
    short8 a1 = *(const short8*)(X + (size_t)(row0 + 16 + lr) * 256 + ks * 32 + lg * 8);
    #pragma unroll
    for (int ct = 0; ct < 16; ++ct) {
      short8 bw = *(const short8*)(WT + (size_t)(ct * 16 + lr) * 256 + ks * 32 + lg * 8);
      acc[0][ct] = __builtin_amdgcn_mfma_f32_16x16x32_bf16(a0, bw, acc[0][ct], 0, 0, 0);
      acc[1][ct] = __builtin_amdgcn_mfma_f32_16x16x32_bf16(a1, bw, acc[1][ct], 0, 0, 0);
    }
  }
  #pragma unroll
  for (int i = 0; i < 2; ++i) {
    #pragma unroll
    for (int ct = 0; ct < 16; ++ct) {
      #pragma unroll
      for (int r = 0; r < 4; ++r) {
        int row = row0 + i * 16 + lg * 4 + r;
        int col = ct * 16 + lr;
        float v = acc[i][ct][r];
        if (MODE == 1) {
          size_t o = (size_t)row * 256 + col;
          outf[o] = resid[o] + v;
        } else {
          int gr = row_base + row;
          int b = gr / 11776; int rem = gr - b * 11776;
          int j = rem >> 8, n = rem & 255;
          size_t o = (((size_t)((b << 8) + n) << 8) + act_t(j)) * 256 + col;
          outf[o] += v;
        }
      }
    }
  }
}

// ---------------- attention: one block per (head, seq); seq len 256, hdim 32 ----------------
__global__ __launch_bounds__(256) void attn_kernel(
    const unsigned short* __restrict__ Q, const unsigned short* __restrict__ K,
    const unsigned short* __restrict__ V, unsigned short* __restrict__ O,
    const int* __restrict__ mask, int seq_base) {
  __shared__ unsigned short Ksh[256][40];    // padded: 2-way max bank conflict
  __shared__ unsigned short Vtsh[32][264];   // V transposed [d][key]
  __shared__ unsigned short Psh[4][16][264]; // per-wave P transpose buffer
  int head = blockIdx.x, seq = blockIdx.y;
  int hc = head * 32;
  size_t sb = (size_t)seq * 65536;
  int tid = threadIdx.x;
  {
    int r = tid;  // one row per thread
    #pragma unroll
    for (int c = 0; c < 4; ++c) {
      *(short8*)&Ksh[r][c * 8] = *(const short8*)(K + sb + (size_t)r * 256 + hc + c * 8);
      short8 vv = *(const short8*)(V + sb + (size_t)r * 256 + hc + c * 8);
      #pragma unroll
      for (int e = 0; e < 8; ++e) Vtsh[c * 8 + e][r] = (unsigned short)vv[e];
    }
  }
  __syncthreads();
  int wv = tid >> 6, lane = tid & 63, lr = lane & 15, lg = lane >> 4;
  const float scale = 0.17677669529663687f;  // 1/sqrt(32)
  int mb = 0;
  if (mask) mb = (seq_base + seq) / TP;
  f32x4 zero = {0.f, 0.f, 0.f, 0.f};
  for (int rt = 0; rt < 4; ++rt) {
    int row0 = wv * 64 + rt * 16;
    short8 aq = *(const short8*)(Q + sb + (size_t)(row0 + lr) * 256 + hc + lg * 8);
    f32x4 s[16];
    #pragma unroll
    for (int ct = 0; ct < 16; ++ct) {
      short8 kb = *(const short8*)&Ksh[ct * 16 + lr][lg * 8];
      s[ct] = __builtin_amdgcn_mfma_f32_16x16x32_bf16(aq, kb, zero, 0, 0, 0);
    }
    #pragma unroll
    for (int ct = 0; ct < 16; ++ct) {
      bool keep = true;
      if (mask) keep = (mask[mb * 256 + ct * 16 + lr] != 0);
      #pragma unroll
      for (int r = 0; r < 4; ++r) {
        float v = s[ct][r] * scale;
        s[ct][r] = keep ? v : -1e9f;
      }
    }
    float mx[4] = {-3e38f, -3e38f, -3e38f, -3e38f};
    #pragma unroll
    for (int ct = 0; ct < 16; ++ct)
      #pragma unroll
      for (int r = 0; r < 4; ++r) mx[r] = fmaxf(mx[r], s[ct][r]);
    #pragma unroll
    for (int off = 1; off < 16; off <<= 1)
      #pragma unroll
      for (int r = 0; r < 4; ++r) mx[r] = fmaxf(mx[r], __shfl_xor(mx[r], off, 64));
    float sum[4] = {0.f, 0.f, 0.f, 0.f};
    #pragma unroll
    for (int ct = 0; ct < 16; ++ct)
      #pragma unroll
      for (int r = 0; r < 4; ++r) {
        float p = __expf(s[ct][r] - mx[r]);
        s[ct][r] = p; sum[r] += p;
      }
    #pragma unroll
    for (int off = 1; off < 16; off <<= 1)
      #pragma unroll
      for (int r = 0; r < 4; ++r) sum[r] += __shfl_xor(sum[r], off, 64);
    float inv[4];
    #pragma unroll
    for (int r = 0; r < 4; ++r) inv[r] = 1.0f / sum[r];
    #pragma unroll
    for (int ct = 0; ct < 16; ++ct)
      #pragma unroll
      for (int r = 0; r < 4; ++r)
        Psh[wv][lg * 4 + r][ct * 16 + lr] = f2bf(s[ct][r] * inv[r]);
    f32x4 o[2] = {zero, zero};
    #pragma unroll
    for (int ks = 0; ks < 8; ++ks) {
      short8 pa = *(const short8*)&Psh[wv][lr][ks * 32 + lg * 8];
      #pragma unroll
      for (int c2 = 0; c2 < 2; ++c2) {
        short8 vbf = *(const short8*)&Vtsh[c2 * 16 + lr][ks * 32 + lg * 8];
        o[c2] = __builtin_amdgcn_mfma_f32_16x16x32_bf16(pa, vbf, o[c2], 0, 0, 0);
      }
    }
    #pragma unroll
    for (int c2 = 0; c2 < 2; ++c2)
      #pragma unroll
      for (int r = 0; r < 4; ++r)
        O[sb + (size_t)(row0 + lg * 4 + r) * 256 + hc + c2 * 16 + lr] = f2bf(o[c2][r]);
  }
}

// ---------------- fused FFN v3: out += gelu(X@W1+b1)@W2 + b2 ----------------
// 64 rows/block, 4 waves. Double-buffered 32KB weight chunks staged via
// global_load_lds with stage-ahead: ONE barrier per chunk. W1 MFMA operands
// swapped so each lane's 4 h-values are ff-consecutive -> b64 Psh writes.
__global__ __launch_bounds__(256) void ffn_kernel(
    const unsigned short* __restrict__ X, const unsigned short* __restrict__ W1F,
    const unsigned short* __restrict__ W2F, const float* __restrict__ b1,
    const float* __restrict__ b2, float* __restrict__ out) {
  __shared__ unsigned short Wbuf[2][16384];  // [buf]: W1s 0..8191 | W2s 8192..16383
  __shared__ unsigned short Psh[4][16][36];  // per-wave P, pitch 36 (bank-clean)
  int tid = threadIdx.x;
  int wv = tid >> 6, lane = tid & 63, lr = lane & 15, lg = lane >> 4;
  int wrow = blockIdx.x * 64 + wv * 16;
  f32x4 zero = {0.f, 0.f, 0.f, 0.f};
  f32x4 oacc[16];
  #pragma unroll
  for (int ct = 0; ct < 16; ++ct) oacc[ct] = zero;
  short8 afrag[8];  // this wave's 16 rows of X, reused across all 32 FF chunks
  #pragma unroll
  for (int ks = 0; ks < 8; ++ks)
    afrag[ks] = *(const short8*)(X + (size_t)(wrow + lr) * 256 + ks * 32 + lg * 8);
  // stage chunk 0 into buf 0: waves 0,1 stage W1 (16x1KB), waves 2,3 stage W2
  #pragma unroll
  for (int i = 0; i < 8; ++i) {
    if (wv < 2) {
      int s = wv * 8 + i;
      load_lds16(W1F + (size_t)s * 512 + lane * 8, &Wbuf[0][s * 512]);
    } else {
      int s = (wv - 2) * 8 + i;
      load_lds16(W2F + (size_t)s * 512 + lane * 8, &Wbuf[0][8192 + s * 512]);
    }
  }
  for (int fc = 0; fc < 32; ++fc) {
    __syncthreads();  // drains vmcnt (stage fc complete) + all waves past chunk fc-1
    int cur = fc & 1;
    if (fc < 31) {
      int nb = cur ^ 1;
      size_t go = (size_t)(fc + 1) * 8192;
      #pragma unroll
      for (int i = 0; i < 8; ++i) {
        if (wv < 2) {
          int s = wv * 8 + i;
          load_lds16(W1F + go + s * 512 + lane * 8, &Wbuf[nb][s * 512]);
        } else {
          int s = (wv - 2) * 8 + i;
          load_lds16(W2F + go + s * 512 + lane * 8, &Wbuf[nb][8192 + s * 512]);
        }
      }
    }
    const unsigned short* W1s = &Wbuf[cur][0];
    const unsigned short* W2s = &Wbuf[cur][8192];
    f32x4 hacc[2];
    hacc[0] = zero; hacc[1] = zero;
    #pragma unroll
    for (int ks = 0; ks < 8; ++ks) {
      #pragma unroll
      for (int ct = 0; ct < 2; ++ct) {
        short8 w1f = *(const short8*)&W1s[(ct * 8 + ks) * 512 + lane * 8];
        // swapped operands: D[ff][xrow] -> lane holds 4 consecutive ff for xrow=lr
        hacc[ct] = __builtin_amdgcn_mfma_f32_16x16x32_bf16(w1f, afrag[ks], hacc[ct], 0, 0, 0);
      }
    }
    #pragma unroll
    for (int ct = 0; ct < 2; ++ct) {
      float4 bb = *(const float4*)(b1 + fc * 32 + ct * 16 + lg * 4);
      ushort4 pk;
      {
        float hv = hacc[ct][0] + bb.x;
        pk.x = f2bf_fast(hv / (1.0f + __expf(-1.5957691216057308f * (hv + 0.044715f * hv * hv * hv))));
        hv = hacc[ct][1] + bb.y;
        pk.y = f2bf_fast(hv / (1.0f + __expf(-1.5957691216057308f * (hv + 0.044715f * hv * hv * hv))));
        hv = hacc[ct][2] + bb.z;
        pk.z = f2bf_fast(hv / (1.0f + __expf(-1.5957691216057308f * (hv + 0.044715f * hv * hv * hv))));
        hv = hacc[ct][3] + bb.w;
        pk.w = f2bf_fast(hv / (1.0f + __expf(-1.5957691216057308f * (hv + 0.044715f * hv * hv * hv))));
      }
      *(ushort4*)&Psh[wv][lr][ct * 16 + lg * 4] = pk;  // xrow=lr, 4 consecutive ff
    }
    short8 pa = *(const short8*)&Psh[wv][lr][lg * 8];
    #pragma unroll
    for (int ct2 = 0; ct2 < 16; ++ct2) {
      short8 bw2 = *(const short8*)&W2s[ct2 * 512 + lane * 8];
      oacc[ct2] = __builtin_amdgcn_mfma_f32_16x16x32_bf16(pa, bw2, oacc[ct2], 0, 0, 0);
    }
  }
  #pragma unroll
  for (int ct = 0; ct < 16; ++ct)
    #pragma unroll
    for (int r = 0; r < 4; ++r) {
      int row = wrow + lg * 4 + r, col = ct * 16 + lr;
      size_t o = (size_t)row * 256 + col;
      out[o] += oacc[ct][r] + b2[col];
    }
}

extern "C" void kernel_launch(void* const* d_in, const int* in_sizes, int n_in,
                              void* d_out, int out_size, void* d_ws, size_t ws_size,
                              hipStream_t stream) {
  (void)in_sizes; (void)n_in; (void)out_size;
  const float* h   = (const float*)d_in[0];
  const int* smask = (const int*)d_in[1];
  const float* ntw = (const float*)d_in[2];
  const float* nsw = (const float*)d_in[3];
  const float* nfw = (const float*)d_in[4];
  const float* wq_t = (const float*)d_in[5];
  const float* wk_t = (const float*)d_in[6];
  const float* wv_t = (const float*)d_in[7];
  const float* wo_t = (const float*)d_in[8];
  const float* wq_s = (const float*)d_in[9];
  const float* wk_s = (const float*)d_in[10];
  const float* wv_s = (const float*)d_in[11];
  const float* wo_s = (const float*)d_in[12];
  const float* w1  = (const float*)d_in[13];
  const float* b1  = (const float*)d_in[14];
  const float* w2  = (const float*)d_in[15];
  const float* b2  = (const float*)d_in[16];
  float* out = (float*)d_out;
  unsigned short* pool = (unsigned short*)d_ws;

  unsigned short* WQKVt = pool;            // 3 consecutive mats
  unsigned short* WOt = pool + 196608;
  unsigned short* WQKVs = pool + 262144;   // 3 consecutive mats
  unsigned short* WOs = pool + 458752;
  unsigned short* W1F = pool + 524288;
  unsigned short* W2F = pool + 786432;

  size_t wbytes = 1048576ull * 2;
  size_t avail = (ws_size > wbytes) ? (ws_size - wbytes) : 0;
  long long scl = (long long)(avail / 524288ull);  // 4 buffers x 128KB per sequence
  int SC = scl < 1 ? 1 : (scl > 512 ? 512 : (int)scl);
  unsigned short* xnorm = pool + 1048576;  // attention output / stage-3 rms output
  unsigned short* qb = xnorm + (size_t)SC * 65536;
  unsigned short* kb = qb + (size_t)SC * 65536;
  unsigned short* vb = kb + (size_t)SC * 65536;

  convw_kernel<<<4096, 256, 0, stream>>>(wq_t, wk_t, wv_t, wo_t, wq_s, wk_s, wv_s,
                                         wo_s, w1, w2, pool);

  // ---- stage 1: time attention over (b,n) sequences (512 of them) ----
  for (int s0 = 0; s0 < 512; s0 += SC) {
    int ns = (512 - s0 < SC) ? (512 - s0) : SC;
    int rows = ns * 256;
    qkv_kernel<0><<<rows / 128, 256, 0, stream>>>(h + (size_t)s0 * 65536, ntw, WQKVt,
                                                  qb, kb, vb, 0);
    attn_kernel<<<dim3(8, ns), 256, 0, stream>>>(qb, kb, vb, xnorm, nullptr, 0);
    gemm256_kernel<1><<<rows / 128, 256, 0, stream>>>(xnorm, WOt,
        h + (size_t)s0 * 65536, out + (size_t)s0 * 65536, 0);
  }

  // ---- stage 2: stock attention over gathered active-t slices (92 sequences) ----
  int SC2 = SC < 92 ? SC : 92;
  for (int s0 = 0; s0 < 92; s0 += SC2) {
    int ns = (92 - s0 < SC2) ? (92 - s0) : SC2;
    int rows = ns * 256;
    qkv_kernel<1><<<rows / 128, 256, 0, stream>>>(out, nsw, WQKVs, qb, kb, vb, s0 * 256);
    attn_kernel<<<dim3(8, ns), 256, 0, stream>>>(qb, kb, vb, xnorm, smask, s0);
    gemm256_kernel<2><<<rows / 128, 256, 0, stream>>>(xnorm, WOs, nullptr, out, s0 * 256);
  }

  // ---- stage 3: FFN ----
  int TCH = SC * 256;
  for (int t0 = 0; t0 < 131072; t0 += TCH) {
    int tc = (131072 - t0 < TCH) ? (131072 - t0) : TCH;
    rms_kernel<<<tc / 4, 256, 0, stream>>>(out + (size_t)t0 * 256, nfw, xnorm, tc);
    ffn_kernel<<<tc / 64, 256, 0, stream>>>(xnorm, W1F, W2F, b1, b2, out + (size_t)t0 * 256);
  }
}

// Round 4
// 955.882 us; speedup vs baseline: 1.3662x; 1.0127x over previous
//
#include <hip/hip_runtime.h>
#include <hip/hip_bf16.h>

typedef __attribute__((ext_vector_type(8))) short short8;
typedef __attribute__((ext_vector_type(4))) float f32x4;

#define TP 46  // active time steps: 30 strided + 16 dense

__device__ __forceinline__ unsigned short f2bf(float f) {  // RNE (weights, one-time)
  unsigned int u = __float_as_uint(f);
  u = (u + 0x7fff + ((u >> 16) & 1)) >> 16;
  return (unsigned short)u;
}
// round-half-up: 2 VALU ops; <=1ulp bias, fine at bf16 threshold
__device__ __forceinline__ unsigned short f2bf_fast(float f) {
  return (unsigned short)((__float_as_uint(f) + 0x8000u) >> 16);
}
__device__ __forceinline__ float fast_rcp(float x) {
#if __has_builtin(__builtin_amdgcn_rcpf)
  return __builtin_amdgcn_rcpf(x);
#else
  return 1.0f / x;
#endif
}
__device__ __forceinline__ float fast_rsq(float x) {
#if __has_builtin(__builtin_amdgcn_rsqf)
  return __builtin_amdgcn_rsqf(x);
#else
  return rsqrtf(x);
#endif
}

__device__ __forceinline__ int act_t(int j) { return j < 30 ? (j << 3) : (210 + j); }

// async 16B/lane global->LDS: lds base must be wave-uniform; HW writes lane i at base+i*16
__device__ __forceinline__ void load_lds16(const unsigned short* g, unsigned short* lds_base) {
#if __has_builtin(__builtin_amdgcn_global_load_lds)
  __builtin_amdgcn_global_load_lds(
      (const __attribute__((address_space(1))) unsigned int*)(unsigned long long)g,
      (__attribute__((address_space(3))) unsigned int*)(unsigned int)(unsigned long long)lds_base,
      16, 0, 0);
#else
  int lane = threadIdx.x & 63;
  *(short8*)(lds_base + lane * 8) = *(const short8*)g;
#endif
}

// ---------------- weight convert + transpose to bf16 ----------------
// pool layout (elem offsets): WQKVt 0 (3 mats), WOt 196608, WQKVs 262144, WOs 458752
// (all WT[c][k]), W1F 524288, W2F 786432 (fragment-ordered for fused FFN).
// W1F: off = ((fc*2+ct)*8+ks)*512 + lane*8 + e  -> w1[(ks*32+lg*8+e)*1024 + fc*32+ct*16+lr]
// W2F: off = (fc*16+ct2)*512 + lane*8 + e2      -> w2[(fc*32+lg*8+e2)*256 + ct2*16+lr]
__global__ __launch_bounds__(256) void convw_kernel(
    const float* __restrict__ wq_t, const float* __restrict__ wk_t,
    const float* __restrict__ wv_t, const float* __restrict__ wo_t,
    const float* __restrict__ wq_s, const float* __restrict__ wk_s,
    const float* __restrict__ wv_s, const float* __restrict__ wo_s,
    const float* __restrict__ w1, const float* __restrict__ w2,
    unsigned short* __restrict__ pool) {
  int idx = blockIdx.x * 256 + threadIdx.x;
  float v;
  if (idx < 524288) {
    int seg = idx >> 16, local = idx & 65535;
    const float* s = (seg == 0) ? wq_t : (seg == 1) ? wk_t : (seg == 2) ? wv_t :
                     (seg == 3) ? wo_t : (seg == 4) ? wq_s : (seg == 5) ? wk_s :
                     (seg == 6) ? wv_s : wo_s;
    int c = local >> 8, k = local & 255;
    v = s[k * 256 + c];
  } else if (idx < 786432) {
    int local = idx - 524288;
    int e = local & 7, t = local >> 3;
    int lane = t & 63, ks = (t >> 6) & 7, ct = (t >> 9) & 1, fc = t >> 10;
    int lr = lane & 15, lg = lane >> 4;
    v = w1[(size_t)(ks * 32 + lg * 8 + e) * 1024 + fc * 32 + ct * 16 + lr];
  } else {
    int local = idx - 786432;
    int e2 = local & 7, t = local >> 3;
    int lane = t & 63, ct2 = (t >> 6) & 15, fc = t >> 10;
    int lr = lane & 15, lg = lane >> 4;
    v = w2[(size_t)(fc * 32 + lg * 8 + e2) * 256 + ct2 * 16 + lr];
  }
  pool[idx] = f2bf(v);
}

// ---------------- fused rmsnorm + QKV projection ----------------
// Block: 128 rows, 4 waves x 32 rows (2 rowtiles). rms in-register (lane holds
// its A-fragment cols; shfl_xor(16),(32) completes the row sum). Then ct-outer
// over 3x16 weight coltiles, B-frags streamed from L2, fresh 8-reg accumulators.
template<int GATHER>
__global__ __launch_bounds__(256) void qkv_kernel(
    const float* __restrict__ src, const float* __restrict__ nw,
    const unsigned short* __restrict__ W,  // 3 consecutive frag-major 256x256 mats
    unsigned short* __restrict__ qb, unsigned short* __restrict__ kb,
    unsigned short* __restrict__ vb, int row_base) {
  int tid = threadIdx.x, wv = tid >> 6, lane = tid & 63, lr = lane & 15, lg = lane >> 4;
  int row0 = blockIdx.x * 128 + wv * 32;
  short8 afrag[2][8];
  #pragma unroll
  for (int rt = 0; rt < 2; ++rt) {
    int lrow = row0 + rt * 16 + lr;
    const float* rp;
    if (GATHER) {
      int gr = row_base + lrow;
      int b = gr / 11776; int rem = gr - b * 11776;
      int j = rem >> 8, n = rem & 255;
      rp = src + (((size_t)((b << 8) + n) << 8) + act_t(j)) * 256;
    } else {
      rp = src + (size_t)lrow * 256;
    }
    float4 x[16];
    #pragma unroll
    for (int ks = 0; ks < 8; ++ks) {
      x[ks * 2]     = *(const float4*)(rp + ks * 32 + lg * 8);
      x[ks * 2 + 1] = *(const float4*)(rp + ks * 32 + lg * 8 + 4);
    }
    float ss = 0.f;
    #pragma unroll
    for (int i = 0; i < 16; ++i)
      ss += x[i].x * x[i].x + x[i].y * x[i].y + x[i].z * x[i].z + x[i].w * x[i].w;
    ss += __shfl_xor(ss, 16, 64);
    ss += __shfl_xor(ss, 32, 64);
    float sc = fast_rsq(ss * 0.00390625f + 1e-6f);
    #pragma unroll
    for (int ks = 0; ks < 8; ++ks) {
      float4 w0 = *(const float4*)(nw + ks * 32 + lg * 8);
      float4 w1_ = *(const float4*)(nw + ks * 32 + lg * 8 + 4);
      short8 af;
      af[0] = (short)f2bf_fast(x[ks * 2].x * sc * w0.x);
      af[1] = (short)f2bf_fast(x[ks * 2].y * sc * w0.y);
      af[2] = (short)f2bf_fast(x[ks * 2].z * sc * w0.z);
      af[3] = (short)f2bf_fast(x[ks * 2].w * sc * w0.w);
      af[4] = (short)f2bf_fast(x[ks * 2 + 1].x * sc * w1_.x);
      af[5] = (short)f2bf_fast(x[ks * 2 + 1].y * sc * w1_.y);
      af[6] = (short)f2bf_fast(x[ks * 2 + 1].z * sc * w1_.z);
      af[7] = (short)f2bf_fast(x[ks * 2 + 1].w * sc * w1_.w);
      afrag[rt][ks] = af;
    }
  }
  f32x4 zero = {0.f, 0.f, 0.f, 0.f};
  #pragma unroll
  for (int m = 0; m < 3; ++m) {
    unsigned short* dst = (m == 0) ? qb : (m == 1) ? kb : vb;
    const unsigned short* wb = W + m * 65536;
    #pragma unroll 4
    for (int ct = 0; ct < 16; ++ct) {
      short8 bw[8];
      #pragma unroll
      for (int ks = 0; ks < 8; ++ks)
        bw[ks] = *(const short8*)(wb + (size_t)(ct * 16 + lr) * 256 + ks * 32 + lg * 8);
      f32x4 a0 = zero, a1 = zero;
      #pragma unroll
      for (int ks = 0; ks < 8; ++ks) {
        a0 = __builtin_amdgcn_mfma_f32_16x16x32_bf16(afrag[0][ks], bw[ks], a0, 0, 0, 0);
        a1 = __builtin_amdgcn_mfma_f32_16x16x32_bf16(afrag[1][ks], bw[ks], a1, 0, 0, 0);
      }
      #pragma unroll
      for (int r = 0; r < 4; ++r) {
        dst[(size_t)(row0 + lg * 4 + r) * 256 + ct * 16 + lr] = f2bf_fast(a0[r]);
        dst[(size_t)(row0 + 16 + lg * 4 + r) * 256 + ct * 16 + lr] = f2bf_fast(a1[r]);
      }
    }
  }
}

// ---------------- GEMM: X[rows x 256] (bf16) @ W (as WT[256][256] bf16) ----------------
// MODE 1: outf = resid + X@W (fp32).  MODE 2: scatter-add into h.
template<int MODE>
__global__ __launch_bounds__(256) void gemm256_kernel(
    const unsigned short* __restrict__ X, const unsigned short* __restrict__ WT,
    const float* __restrict__ resid, float* __restrict__ outf, int row_base) {
  int wv = threadIdx.x >> 6, lane = threadIdx.x & 63;
  int lr = lane & 15, lg = lane >> 4;
  int row0 = blockIdx.x * 128 + wv * 32;
  f32x4 zero = {0.f, 0.f, 0.f, 0.f};
  f32x4 acc[2][16];
  #pragma unroll
  for (int i = 0; i < 2; ++i)
    #pragma unroll
    for (int ct = 0; ct < 16; ++ct) acc[i][ct] = zero;
  #pragma unroll
  for (int ks = 0; ks < 8; ++ks) {
    short8 a0 = *(const short8*)(X + (size_t)(row0 + lr) * 256 + ks * 32 + lg * 8);
    short8 a1 = *(const short8*)(X + (size_t)(row0 + 16 + lr) * 256 + ks * 32 + lg * 8);
    #pragma unroll
    for (int ct = 0; ct < 16; ++ct) {
      short8 bw = *(const short8*)(WT + (size_t)(ct * 16 + lr) * 256 + ks * 32 + lg * 8);
      acc[0][ct] = __builtin_amdgcn_mfma_f32_16x16x32_bf16(a0, bw, acc[0][ct], 0, 0, 0);
      acc[1][ct] = __builtin_amdgcn_mfma_f32_16x16x32_bf16(a1, bw, acc[1][ct], 0, 0, 0);
    }
  }
  #pragma unroll
  for (int i = 0; i < 2; ++i) {
    #pragma unroll
    for (int ct = 0; ct < 16; ++ct) {
      #pragma unroll
      for (int r = 0; r < 4; ++r) {
        int row = row0 + i * 16 + lg * 4 + r;
        int col = ct * 16 + lr;
        float v = acc[i][ct][r];
        if (MODE == 1) {
          size_t o = (size_t)row * 256 + col;
          outf[o] = resid[o] + v;
        } else {
          int gr = row_base + row;
          int b = gr / 11776; int rem = gr - b * 11776;
          int j = rem >> 8, n = rem & 255;
          size_t o = (((size_t)((b << 8) + n) << 8) + act_t(j)) * 256 + col;
          outf[o] += v;
        }
      }
    }
  }
}

// ---------------- attention: one block per (head, seq); seq len 256, hdim 32 ----------------
__global__ __launch_bounds__(256) void attn_kernel(
    const unsigned short* __restrict__ Q, const unsigned short* __restrict__ K,
    const unsigned short* __restrict__ V, unsigned short* __restrict__ O,
    const int* __restrict__ mask, int seq_base) {
  __shared__ unsigned short Ksh[256][40];    // padded: 2-way max bank conflict
  __shared__ unsigned short Vtsh[32][264];   // V transposed [d][key]
  __shared__ unsigned short Psh[4][16][264]; // per-wave P transpose buffer
  int head = blockIdx.x, seq = blockIdx.y;
  int hc = head * 32;
  size_t sb = (size_t)seq * 65536;
  int tid = threadIdx.x;
  {
    int r = tid;  // one row per thread
    #pragma unroll
    for (int c = 0; c < 4; ++c) {
      *(short8*)&Ksh[r][c * 8] = *(const short8*)(K + sb + (size_t)r * 256 + hc + c * 8);
      short8 vv = *(const short8*)(V + sb + (size_t)r * 256 + hc + c * 8);
      #pragma unroll
      for (int e = 0; e < 8; ++e) Vtsh[c * 8 + e][r] = (unsigned short)vv[e];
    }
  }
  __syncthreads();
  int wv = tid >> 6, lane = tid & 63, lr = lane & 15, lg = lane >> 4;
  const float scale = 0.17677669529663687f;  // 1/sqrt(32)
  int mb = 0;
  if (mask) mb = (seq_base + seq) / TP;
  f32x4 zero = {0.f, 0.f, 0.f, 0.f};
  for (int rt = 0; rt < 4; ++rt) {
    int row0 = wv * 64 + rt * 16;
    short8 aq = *(const short8*)(Q + sb + (size_t)(row0 + lr) * 256 + hc + lg * 8);
    f32x4 s[16];
    #pragma unroll
    for (int ct = 0; ct < 16; ++ct) {
      short8 kb = *(const short8*)&Ksh[ct * 16 + lr][lg * 8];
      s[ct] = __builtin_amdgcn_mfma_f32_16x16x32_bf16(aq, kb, zero, 0, 0, 0);
    }
    #pragma unroll
    for (int ct = 0; ct < 16; ++ct) {
      bool keep = true;
      if (mask) keep = (mask[mb * 256 + ct * 16 + lr] != 0);
      #pragma unroll
      for (int r = 0; r < 4; ++r) {
        float v = s[ct][r] * scale;
        s[ct][r] = keep ? v : -1e9f;
      }
    }
    float mx[4] = {-3e38f, -3e38f, -3e38f, -3e38f};
    #pragma unroll
    for (int ct = 0; ct < 16; ++ct)
      #pragma unroll
      for (int r = 0; r < 4; ++r) mx[r] = fmaxf(mx[r], s[ct][r]);
    #pragma unroll
    for (int off = 1; off < 16; off <<= 1)
      #pragma unroll
      for (int r = 0; r < 4; ++r) mx[r] = fmaxf(mx[r], __shfl_xor(mx[r], off, 64));
    float sum[4] = {0.f, 0.f, 0.f, 0.f};
    #pragma unroll
    for (int ct = 0; ct < 16; ++ct)
      #pragma unroll
      for (int r = 0; r < 4; ++r) {
        float p = __expf(s[ct][r] - mx[r]);
        s[ct][r] = p; sum[r] += p;
      }
    #pragma unroll
    for (int off = 1; off < 16; off <<= 1)
      #pragma unroll
      for (int r = 0; r < 4; ++r) sum[r] += __shfl_xor(sum[r], off, 64);
    float inv[4];
    #pragma unroll
    for (int r = 0; r < 4; ++r) inv[r] = fast_rcp(sum[r]);
    #pragma unroll
    for (int ct = 0; ct < 16; ++ct)
      #pragma unroll
      for (int r = 0; r < 4; ++r)
        Psh[wv][lg * 4 + r][ct * 16 + lr] = f2bf_fast(s[ct][r] * inv[r]);
    f32x4 o[2] = {zero, zero};
    #pragma unroll
    for (int ks = 0; ks < 8; ++ks) {
      short8 pa = *(const short8*)&Psh[wv][lr][ks * 32 + lg * 8];
      #pragma unroll
      for (int c2 = 0; c2 < 2; ++c2) {
        short8 vbf = *(const short8*)&Vtsh[c2 * 16 + lr][ks * 32 + lg * 8];
        o[c2] = __builtin_amdgcn_mfma_f32_16x16x32_bf16(pa, vbf, o[c2], 0, 0, 0);
      }
    }
    #pragma unroll
    for (int c2 = 0; c2 < 2; ++c2)
      #pragma unroll
      for (int r = 0; r < 4; ++r)
        O[sb + (size_t)(row0 + lg * 4 + r) * 256 + hc + c2 * 16 + lr] = f2bf_fast(o[c2][r]);
  }
}

// ---------------- fused rms + FFN v4: hio += gelu(rms(hio)@W1+b1)@W2 + b2 ----------------
// 512 threads (8 waves), 128 rows/block, double-buffered 32KB weight chunks via
// global_load_lds, ONE barrier per chunk. 2 blocks/CU (LDS 73KB) x 8 waves =
// 4 waves/SIMD. rms fused in-register (two passes over row to cap VGPR at 128).
__global__ __launch_bounds__(512, 4) void ffn_kernel(
    float* __restrict__ hio, const float* __restrict__ nw,
    const unsigned short* __restrict__ W1F, const unsigned short* __restrict__ W2F,
    const float* __restrict__ b1, const float* __restrict__ b2) {
  __shared__ unsigned short Wbuf[2][16384];  // [buf]: W1s 0..8191 | W2s 8192..16383
  __shared__ unsigned short Psh[8][16][36];  // per-wave P, pitch 36 (bank-clean)
  int tid = threadIdx.x;
  int wv = tid >> 6, lane = tid & 63, lr = lane & 15, lg = lane >> 4;
  int wrow = blockIdx.x * 128 + wv * 16;
  const float* rp = hio + (size_t)(wrow + lr) * 256;
  // pass 1: sum-of-squares (4 lanes with same lr share the row)
  float ss = 0.f;
  #pragma unroll
  for (int ks = 0; ks < 8; ++ks) {
    float4 a = *(const float4*)(rp + ks * 32 + lg * 8);
    float4 b = *(const float4*)(rp + ks * 32 + lg * 8 + 4);
    ss += a.x * a.x + a.y * a.y + a.z * a.z + a.w * a.w;
    ss += b.x * b.x + b.y * b.y + b.z * b.z + b.w * b.w;
  }
  ss += __shfl_xor(ss, 16, 64);
  ss += __shfl_xor(ss, 32, 64);
  float sc = fast_rsq(ss * 0.00390625f + 1e-6f);
  // stage chunk 0 into buf 0 (each wave stages 4 x 1KB segments)
  #pragma unroll
  for (int i = 0; i < 4; ++i) {
    int s = wv * 4 + i;
    const unsigned short* srcp = (s < 16) ? (W1F + (size_t)s * 512)
                                          : (W2F + (size_t)(s - 16) * 512);
    load_lds16(srcp + lane * 8, &Wbuf[0][s * 512]);
  }
  // pass 2: rebuild row (L2-hit) and pack normalized bf16 A-fragments
  short8 afrag[8];
  #pragma unroll
  for (int ks = 0; ks < 8; ++ks) {
    float4 a = *(const float4*)(rp + ks * 32 + lg * 8);
    float4 b = *(const float4*)(rp + ks * 32 + lg * 8 + 4);
    float4 wa = *(const float4*)(nw + ks * 32 + lg * 8);
    float4 wb = *(const float4*)(nw + ks * 32 + lg * 8 + 4);
    short8 af;
    af[0] = (short)f2bf_fast(a.x * sc * wa.x);
    af[1] = (short)f2bf_fast(a.y * sc * wa.y);
    af[2] = (short)f2bf_fast(a.z * sc * wa.z);
    af[3] = (short)f2bf_fast(a.w * sc * wa.w);
    af[4] = (short)f2bf_fast(b.x * sc * wb.x);
    af[5] = (short)f2bf_fast(b.y * sc * wb.y);
    af[6] = (short)f2bf_fast(b.z * sc * wb.z);
    af[7] = (short)f2bf_fast(b.w * sc * wb.w);
    afrag[ks] = af;
  }
  f32x4 zero = {0.f, 0.f, 0.f, 0.f};
  f32x4 oacc[16];
  #pragma unroll
  for (int ct = 0; ct < 16; ++ct) oacc[ct] = zero;
  for (int fc = 0; fc < 32; ++fc) {
    __syncthreads();  // drains vmcnt: stage of chunk fc complete; waves synced
    int cur = fc & 1;
    if (fc < 31) {
      size_t go = (size_t)(fc + 1) * 8192;
      #pragma unroll
      for (int i = 0; i < 4; ++i) {
        int s = wv * 4 + i;
        const unsigned short* srcp = (s < 16) ? (W1F + go + (size_t)s * 512)
                                              : (W2F + go + (size_t)(s - 16) * 512);
        load_lds16(srcp + lane * 8, &Wbuf[cur ^ 1][s * 512]);
      }
    }
    const unsigned short* W1s = &Wbuf[cur][0];
    const unsigned short* W2s = &Wbuf[cur][8192];
    f32x4 hacc[2];
    hacc[0] = zero; hacc[1] = zero;
    #pragma unroll
    for (int ks = 0; ks < 8; ++ks) {
      #pragma unroll
      for (int ct = 0; ct < 2; ++ct) {
        short8 w1f = *(const short8*)&W1s[(ct * 8 + ks) * 512 + lane * 8];
        // swapped operands: D[ff][xrow] -> lane holds 4 consecutive ff for xrow=lr
        hacc[ct] = __builtin_amdgcn_mfma_f32_16x16x32_bf16(w1f, afrag[ks], hacc[ct], 0, 0, 0);
      }
    }
    #pragma unroll
    for (int ct = 0; ct < 2; ++ct) {
      float4 bb = *(const float4*)(b1 + fc * 32 + ct * 16 + lg * 4);
      ushort4 pk;
      {
        float hv = hacc[ct][0] + bb.x;
        pk.x = f2bf_fast(hv * fast_rcp(1.0f + __expf(-1.5957691216057308f * fmaf(0.044715f * hv, hv * hv, hv))));
        hv = hacc[ct][1] + bb.y;
        pk.y = f2bf_fast(hv * fast_rcp(1.0f + __expf(-1.5957691216057308f * fmaf(0.044715f * hv, hv * hv, hv))));
        hv = hacc[ct][2] + bb.z;
        pk.z = f2bf_fast(hv * fast_rcp(1.0f + __expf(-1.5957691216057308f * fmaf(0.044715f * hv, hv * hv, hv))));
        hv = hacc[ct][3] + bb.w;
        pk.w = f2bf_fast(hv * fast_rcp(1.0f + __expf(-1.5957691216057308f * fmaf(0.044715f * hv, hv * hv, hv))));
      }
      *(ushort4*)&Psh[wv][lr][ct * 16 + lg * 4] = pk;  // xrow=lr, 4 consecutive ff
    }
    short8 pa = *(const short8*)&Psh[wv][lr][lg * 8];
    #pragma unroll
    for (int ct2 = 0; ct2 < 16; ++ct2) {
      short8 bw2 = *(const short8*)&W2s[ct2 * 512 + lane * 8];
      oacc[ct2] = __builtin_amdgcn_mfma_f32_16x16x32_bf16(pa, bw2, oacc[ct2], 0, 0, 0);
    }
  }
  #pragma unroll
  for (int ct = 0; ct < 16; ++ct)
    #pragma unroll
    for (int r = 0; r < 4; ++r) {
      int row = wrow + lg * 4 + r, col = ct * 16 + lr;
      size_t o = (size_t)row * 256 + col;
      hio[o] += oacc[ct][r] + b2[col];
    }
}

extern "C" void kernel_launch(void* const* d_in, const int* in_sizes, int n_in,
                              void* d_out, int out_size, void* d_ws, size_t ws_size,
                              hipStream_t stream) {
  (void)in_sizes; (void)n_in; (void)out_size;
  const float* h   = (const float*)d_in[0];
  const int* smask = (const int*)d_in[1];
  const float* ntw = (const float*)d_in[2];
  const float* nsw = (const float*)d_in[3];
  const float* nfw = (const float*)d_in[4];
  const float* wq_t = (const float*)d_in[5];
  const float* wk_t = (const float*)d_in[6];
  const float* wv_t = (const float*)d_in[7];
  const float* wo_t = (const float*)d_in[8];
  const float* wq_s = (const float*)d_in[9];
  const float* wk_s = (const float*)d_in[10];
  const float* wv_s = (const float*)d_in[11];
  const float* wo_s = (const float*)d_in[12];
  const float* w1  = (const float*)d_in[13];
  const float* b1  = (const float*)d_in[14];
  const float* w2  = (const float*)d_in[15];
  const float* b2  = (const float*)d_in[16];
  float* out = (float*)d_out;
  unsigned short* pool = (unsigned short*)d_ws;

  unsigned short* WQKVt = pool;            // 3 consecutive mats
  unsigned short* WOt = pool + 196608;
  unsigned short* WQKVs = pool + 262144;   // 3 consecutive mats
  unsigned short* WOs = pool + 458752;
  unsigned short* W1F = pool + 524288;
  unsigned short* W2F = pool + 786432;

  size_t wbytes = 1048576ull * 2;
  size_t avail = (ws_size > wbytes) ? (ws_size - wbytes) : 0;
  long long scl = (long long)(avail / 524288ull);  // 4 buffers x 128KB per sequence
  int SC = scl < 1 ? 1 : (scl > 512 ? 512 : (int)scl);
  unsigned short* xnorm = pool + 1048576;  // attention output buffer
  unsigned short* qb = xnorm + (size_t)SC * 65536;
  unsigned short* kb = qb + (size_t)SC * 65536;
  unsigned short* vb = kb + (size_t)SC * 65536;

  convw_kernel<<<4096, 256, 0, stream>>>(wq_t, wk_t, wv_t, wo_t, wq_s, wk_s, wv_s,
                                         wo_s, w1, w2, pool);

  // ---- stage 1: time attention over (b,n) sequences (512 of them) ----
  for (int s0 = 0; s0 < 512; s0 += SC) {
    int ns = (512 - s0 < SC) ? (512 - s0) : SC;
    int rows = ns * 256;
    qkv_kernel<0><<<rows / 128, 256, 0, stream>>>(h + (size_t)s0 * 65536, ntw, WQKVt,
                                                  qb, kb, vb, 0);
    attn_kernel<<<dim3(8, ns), 256, 0, stream>>>(qb, kb, vb, xnorm, nullptr, 0);
    gemm256_kernel<1><<<rows / 128, 256, 0, stream>>>(xnorm, WOt,
        h + (size_t)s0 * 65536, out + (size_t)s0 * 65536, 0);
  }

  // ---- stage 2: stock attention over gathered active-t slices (92 sequences) ----
  int SC2 = SC < 92 ? SC : 92;
  for (int s0 = 0; s0 < 92; s0 += SC2) {
    int ns = (92 - s0 < SC2) ? (92 - s0) : SC2;
    int rows = ns * 256;
    qkv_kernel<1><<<rows / 128, 256, 0, stream>>>(out, nsw, WQKVs, qb, kb, vb, s0 * 256);
    attn_kernel<<<dim3(8, ns), 256, 0, stream>>>(qb, kb, vb, xnorm, smask, s0);
    gemm256_kernel<2><<<rows / 128, 256, 0, stream>>>(xnorm, WOs, nullptr, out, s0 * 256);
  }

  // ---- stage 3: fused rms + FFN (single dispatch, 1024 blocks x 512 threads) ----
  ffn_kernel<<<1024, 512, 0, stream>>>(out, nfw, W1F, W2F, b1, b2);
}